// Round 9
// baseline (542.622 us; speedup 1.0000x reference)
//
#include <hip/hip_runtime.h>
#include <math.h>

#define B_   64
#define NPB  3468            // points (visual words) per batch
#define NPTS (B_ * NPB)      // 221952
#define KC   248
#define D_   64
#define NV   (KC * D_)       // 15872 per-batch vlad elements
#define OCT  8               // norms: chunks per batch
#define N4PB (NPB * D_ / 4)  // 55488 float4s per batch
#define N4CH (N4PB / OCT)    // 6936 float4s per chunk
#define CHPB 55              // aggregation chunks per batch
#define APAD 65
#define SLIM 64              // sorted code rows staged in LDS
#define NBLK (NPTS / 256)    // 867 point-blocks
#define ZBLK 128             // fallback: extra zeroing blocks
#define ZN4  261888          // float4s in zero region (counts+Sacc+vacc)

// ------------------------- workspace offsets (bytes) -------------------------
#define OFF_PARTIAL 0u        // 131072
#define OFF_COUNTS  131072u   // 63488   -- zero region start
#define OFF_SACC    194560u   // 63488
#define OFF_VACC    258048u   // 4063232 -- zero region end = 4321280
#define OFF_KOUT    4321280u  // 221952
#define OFF_RINV    4543232u  // 887808
#define OFF_RANK    5431040u  // 443904
#define OFF_SPIDX   5874944u  // 443904
#define OFF_SRINV   6318848u  // 887808
#define OFF_SKBUF   7206656u  // 221952
#define OFF_BAR     7428608u  // 64
#define OFF_HNS     7428672u  // 1024
#define OFF_KSRT    7429696u  // 256
#define OFF_INVN    7429952u  // 16384 (fallback only)
#define OFF_SCODES  7446336u  // 63488
#define OFF_BASEP   7509824u  // 63488 (fallback only) -> end 7573312

// ---------------------------------------------------------------- grid barrier
__device__ __forceinline__ void grid_barrier(unsigned int* bar, int idx) {
    __threadfence();                       // release this thread's prior writes
    __syncthreads();
    if (threadIdx.x == 0) {
        unsigned int* cnt = bar + idx * 2;
        unsigned int* gen = bar + idx * 2 + 1;
        unsigned int old = __hip_atomic_fetch_add(cnt, 1u, __ATOMIC_ACQ_REL,
                                                  __HIP_MEMORY_SCOPE_AGENT);
        if (old == gridDim.x - 1) {
            __hip_atomic_store(gen, 1u, __ATOMIC_RELEASE, __HIP_MEMORY_SCOPE_AGENT);
        } else {
            while (!__hip_atomic_load(gen, __ATOMIC_ACQUIRE, __HIP_MEMORY_SCOPE_AGENT)) {
                __builtin_amdgcn_s_sleep(2);
            }
        }
    }
    __syncthreads();
    __threadfence();                       // acquire: invalidate before reading
}

__global__ __launch_bounds__(64) void init_bar_kernel(unsigned int* bar) {
    if (threadIdx.x < 16) bar[threadIdx.x] = 0u;
}

// ================================ MEGA KERNEL ================================
__global__ __launch_bounds__(256, 2) void vlad_mega(
    const float* __restrict__ feat, const float* __restrict__ codes,
    float* __restrict__ partial, int* __restrict__ counts,
    float* __restrict__ Sacc, float* __restrict__ vacc,
    float4* __restrict__ zbase, unsigned char* __restrict__ kout,
    float* __restrict__ rinvout, unsigned short* __restrict__ rankout,
    unsigned short* __restrict__ spidx, float* __restrict__ srinv,
    unsigned char* __restrict__ skbuf, float* __restrict__ hns,
    unsigned char* __restrict__ ksrt, float* __restrict__ scodes,
    unsigned int* __restrict__ bar, float* __restrict__ out)
{
    __shared__ __align__(16) char smem[24576];
    int t = threadIdx.x;
    int lane = t & 63, wvid = t >> 6;
    const float4* c4 = (const float4*)codes;
    const float4* sc4g = (const float4*)scodes;

    // ===== Phase A: zero acc region + sumsq partials + code sort (last vb) =====
    {
        const float4 zf = make_float4(0.f, 0.f, 0.f, 0.f);
        for (int i = blockIdx.x * 256 + t; i < ZN4; i += gridDim.x * 256) zbase[i] = zf;

        for (int vb = blockIdx.x; vb < B_ * OCT + 1; vb += gridDim.x) {
            if (vb == B_ * OCT) {
                // code half-norms + hn-ascending sort + permuted code table
                float* shn = (float*)smem;                 // 992 B
                for (int base2 = 0; base2 < KC * D_; base2 += 256) {
                    float c = codes[base2 + t];
                    float cc = c * c;
                    #pragma unroll
                    for (int off = 32; off > 0; off >>= 1) cc += __shfl_down(cc, off);
                    if (lane == 0) shn[(base2 >> 6) + wvid] = 0.5f * cc;
                }
                __syncthreads();
                if (t < KC) {
                    float myhn = shn[t];
                    int rank = 0;
                    for (int j = 0; j < KC; ++j) {
                        float h = shn[j];
                        rank += (h < myhn) || (h == myhn && j < t);
                    }
                    hns[rank] = myhn;
                    ksrt[rank] = (unsigned char)t;
                    const float4* src = c4 + t * 16;
                    float4* dst = (float4*)(scodes + rank * D_);
                    #pragma unroll
                    for (int j = 0; j < 16; ++j) dst[j] = src[j];
                }
                __syncthreads();
                continue;
            }
            int b = vb >> 3, o = vb & 7;
            float4* red = (float4*)smem;                   // 4 KB
            const float4* f = (const float4*)(feat + (size_t)b * (NPB * D_));
            float ax = 0.f, ay = 0.f, az = 0.f, aw = 0.f;
            for (int j = 0; j < (N4CH + 255) / 256; ++j) {
                int loc = t + j * 256;
                if (loc < N4CH) {
                    float4 a = f[o * N4CH + loc];
                    ax += a.x * a.x; ay += a.y * a.y; az += a.z * a.z; aw += a.w * a.w;
                }
            }
            red[t] = make_float4(ax, ay, az, aw);
            __syncthreads();
            if (t < 16) {   // dim-group of i4 = (t + 8o) & 15
                int t0 = (t - 8 * o) & 15;
                float sx = 0.f, sy = 0.f, sz = 0.f, sw = 0.f;
                #pragma unroll
                for (int j = 0; j < 16; ++j) {
                    float4 a = red[t0 + 16 * j];
                    sx += a.x; sy += a.y; sz += a.z; sw += a.w;
                }
                float* dst = partial + ((size_t)(b * OCT + o)) * D_ + 4 * t;
                dst[0] = sx; dst[1] = sy; dst[2] = sz; dst[3] = sw;
            }
            __syncthreads();
        }
    }
    grid_barrier(bar, 0);

    // ===== Phase B: assignment (per-block inv-norm derive + CS pruning) ========
    {
        float4* lc         = (float4*)smem;                    // 16384
        float*  lhns       = (float*)(smem + 16384);           //   992
        float*  invl       = (float*)(smem + 17376);           //   512
        int*    hist       = (int*)  (smem + 17888);           //  1984
        int*    gbase      = (int*)  (smem + 19872);           //  1984
        unsigned char* lks = (unsigned char*)(smem + 21856);   //   248

        for (int vb = blockIdx.x; vb < NBLK; vb += gridDim.x) {
            __syncthreads();                                   // LDS reuse guard
            int bfirst = (vb * 256) / NPB;
            for (int i = t; i < SLIM * 16; i += 256) lc[i] = sc4g[i];
            for (int i = t; i < KC; i += 256) { lhns[i] = hns[i]; lks[i] = ksrt[i]; }
            if (t < 128) {
                int lb2 = t >> 6, d = t & 63;
                int b2 = bfirst + lb2;
                if (b2 < B_) {
                    float s = 0.f;
                    #pragma unroll
                    for (int o = 0; o < OCT; ++o)
                        s += partial[((size_t)(b2 * OCT + o)) * D_ + d];
                    invl[t] = 1.f / fmaxf(sqrtf(s), 1e-12f);
                }
            }
            for (int i = t; i < 2 * KC; i += 256) hist[i] = 0;
            __syncthreads();

            int p = vb * 256 + t;
            int b = p / NPB;
            int lb = b - bfirst;
            float v[D_];
            float q = 0.f;
            {
                const float4* f0 = (const float4*)(feat + (size_t)p * D_);
                const float4* n0 = ((const float4*)invl) + lb * 16;
                #pragma unroll
                for (int j = 0; j < 16; ++j) {
                    float4 a = f0[j], w = n0[j];
                    v[4*j+0] = a.x * w.x; v[4*j+1] = a.y * w.y;
                    v[4*j+2] = a.z * w.z; v[4*j+3] = a.w * w.w;
                    q += v[4*j+0]*v[4*j+0] + v[4*j+1]*v[4*j+1]
                       + v[4*j+2]*v[4*j+2] + v[4*j+3]*v[4*j+3];
                }
            }
            float bwn = sqrtf(q);
            float best = -3.0e38f;
            int kb = 0;
            int i = 0;
            for (; i < SLIM; ++i) {
                float hn = lhns[i];
                float bnd = fmaf(bwn, sqrtf(hn + hn), -hn);   // Cauchy-Schwarz
                if (__all(bnd + 1e-3f < best)) break;         // monotone -> safe
                float a0 = 0.f, a1 = 0.f, a2 = 0.f, a3 = 0.f;
                #pragma unroll
                for (int j = 0; j < 16; ++j) {
                    float4 c = lc[i * 16 + j];
                    a0 = fmaf(v[4*j+0], c.x, a0); a1 = fmaf(v[4*j+1], c.y, a1);
                    a2 = fmaf(v[4*j+2], c.z, a2); a3 = fmaf(v[4*j+3], c.w, a3);
                }
                float s = (a0 + a1) + (a2 + a3) - hn;
                if (s > best) { best = s; kb = i; }
            }
            if (i == SLIM) {                                  // rare tail
                for (; i < KC; ++i) {
                    float hn = lhns[i];
                    float bnd = fmaf(bwn, sqrtf(hn + hn), -hn);
                    if (__all(bnd + 1e-3f < best)) break;
                    const float4* cr = sc4g + i * 16;
                    float a0 = 0.f, a1 = 0.f, a2 = 0.f, a3 = 0.f;
                    #pragma unroll
                    for (int j = 0; j < 16; ++j) {
                        float4 c = cr[j];
                        a0 = fmaf(v[4*j+0], c.x, a0); a1 = fmaf(v[4*j+1], c.y, a1);
                        a2 = fmaf(v[4*j+2], c.z, a2); a3 = fmaf(v[4*j+3], c.w, a3);
                    }
                    float s = (a0 + a1) + (a2 + a3) - hn;
                    if (s > best) { best = s; kb = i; }
                }
            }
            int k0 = (int)lks[kb];
            float rinv = 1.f / (sqrtf(fmaxf(q - 2.f * best, 0.f)) + 1e-8f);
            kout[p] = (unsigned char)k0;
            rinvout[p] = rinv;
            int rloc = atomicAdd(&hist[lb * KC + k0], 1);     // block-local rank
            __syncthreads();
            for (int j2 = t; j2 < 2 * KC; j2 += 256) {        // reserve ranges
                int h = hist[j2];
                if (h > 0) gbase[j2] = atomicAdd(&counts[bfirst * KC + j2], h);
            }
            __syncthreads();
            rankout[p] = (unsigned short)(gbase[lb * KC + k0] + rloc);
        }
    }
    grid_barrier(bar, 1);

    // ===== Phase C: scatter (per-block prefix recompute) =======================
    {
        int* lcnt  = (int*)smem;             // 1984
        int* lbase = (int*)(smem + 1984);    // 1984
        for (int vb = blockIdx.x; vb < NBLK; vb += gridDim.x) {
            __syncthreads();
            int bfirst = (vb * 256) / NPB, blast = (vb * 256 + 255) / NPB;
            int nb = blast - bfirst + 1;     // 1 or 2
            for (int i = t; i < nb * KC; i += 256) lcnt[i] = counts[bfirst * KC + i];
            __syncthreads();
            if (t < nb) {
                int run = 0;
                for (int k = 0; k < KC; ++k) { lbase[t * KC + k] = run; run += lcnt[t * KC + k]; }
            }
            __syncthreads();
            int p = vb * 256 + t;
            int b = p / NPB;
            int lb = b - bfirst;
            int k = (int)kout[p];
            int pos = b * NPB + lbase[lb * KC + k] + (int)rankout[p];
            spidx[pos] = (unsigned short)(p - b * NPB);
            srinv[pos] = rinvout[p];
            skbuf[pos] = (unsigned char)k;
        }
    }
    grid_barrier(bar, 2);

    // ===== Phase D: load-balanced segmented aggregation ========================
    {
        for (int chunk = blockIdx.x * 4 + wvid; chunk < B_ * CHPB; chunk += gridDim.x * 4) {
            int b = chunk / CHPB, j = chunk % CHPB;
            int c0 = j * 64;
            int len = NPB - c0; if (len > 64) len = 64;
            int sbase = b * NPB;
            int pos = sbase + c0 + ((lane < len) ? lane : 0);
            int myp = (int)spidx[pos];
            int myk = (int)skbuf[pos];
            float myr = srinv[pos];
            const float* fb = feat + (size_t)sbase * D_ + lane;

            float acc = 0.f, Sr = 0.f;
            int kcur = -1;
            for (int i = 0; i < len; i += 4) {
                int n = len - i; if (n > 4) n = 4;
                float x[4], rr[4];
                int kk[4];
                #pragma unroll
                for (int u = 0; u < 4; ++u) {
                    if (u < n) {
                        int pp = __shfl(myp, i + u);
                        kk[u] = __shfl(myk, i + u);
                        rr[u] = __shfl(myr, i + u);
                        x[u] = fb[(size_t)pp * D_];
                    }
                }
                for (int u = 0; u < n; ++u) {
                    if (kk[u] != kcur) {
                        if (kcur >= 0) {
                            atomicAdd(vacc + ((size_t)b * KC + kcur) * D_ + lane, acc);
                            if (lane == 0) atomicAdd(Sacc + b * KC + kcur, Sr);
                        }
                        kcur = kk[u]; acc = 0.f; Sr = 0.f;
                    }
                    acc = fmaf(x[u], rr[u], acc);
                    Sr += rr[u];
                }
            }
            if (kcur >= 0) {
                atomicAdd(vacc + ((size_t)b * KC + kcur) * D_ + lane, acc);
                if (lane == 0) atomicAdd(Sacc + b * KC + kcur, Sr);
            }
        }
    }
    grid_barrier(bar, 3);

    // ===== Phase E: finalize vlad + per-batch standardize ======================
    {
        double* rs    = (double*)smem;            // 2048
        double* rss   = (double*)(smem + 2048);   // 2048
        float*  Sl    = (float*)(smem + 4096);    //  992
        float*  invl2 = (float*)(smem + 5088);    //  256
        float*  fms   = (float*)(smem + 5344);    //    8
        for (int vb = blockIdx.x; vb < B_; vb += gridDim.x) {
            __syncthreads();
            int b = vb;
            if (t < KC) Sl[t] = Sacc[b * KC + t];
            if (t < D_) {
                float s = 0.f;
                #pragma unroll
                for (int o = 0; o < OCT; ++o)
                    s += partial[((size_t)(b * OCT + o)) * D_ + t];
                invl2[t] = 1.f / fmaxf(sqrtf(s), 1e-12f);
            }
            __syncthreads();
            const float* va = vacc + (size_t)b * NV;
            double s = 0.0, ss = 0.0;
            for (int i = t; i < NV; i += 256) {
                int k = i >> 6, d = i & 63;
                float v = invl2[d] * va[i] - codes[i] * Sl[k];
                s += (double)v;
                ss += (double)v * (double)v;
            }
            rs[t] = s; rss[t] = ss;
            __syncthreads();
            for (int off = 128; off > 0; off >>= 1) {
                if (t < off) { rs[t] += rs[t + off]; rss[t] += rss[t + off]; }
                __syncthreads();
            }
            if (t == 0) {
                double S = rs[0], SS = rss[0];
                double mean = S / (double)NV;
                double var = (SS - S * S / (double)NV) / (double)(NV - 1);
                double sd = sqrt(var > 0.0 ? var : 0.0);
                fms[0] = (float)mean;
                fms[1] = (float)(1.0 / (sd + 1e-8));
            }
            __syncthreads();
            float m = fms[0], sc = fms[1];
            float* row = out + (size_t)b * NV;
            for (int i = t; i < NV; i += 256) {
                int k = i >> 6, d = i & 63;
                float v = invl2[d] * va[i] - codes[i] * Sl[k];
                row[i] = (v - m) * sc;
            }
        }
    }
}

// =========================== FALLBACK (round-7 chain) ========================
__global__ __launch_bounds__(256) void norms_part_kernel(const float* __restrict__ feat,
                                                         float* __restrict__ partial,
                                                         float4* __restrict__ zbase) {
    if (blockIdx.x >= B_ * OCT) {
        int z = blockIdx.x - B_ * OCT;
        const float4 zf = make_float4(0.f, 0.f, 0.f, 0.f);
        for (int i = z * 256 + threadIdx.x; i < ZN4; i += ZBLK * 256) zbase[i] = zf;
        return;
    }
    int b = blockIdx.x >> 3, o = blockIdx.x & 7, t = threadIdx.x;
    const float4* f = (const float4*)(feat + (size_t)b * (NPB * D_));
    float ax = 0.f, ay = 0.f, az = 0.f, aw = 0.f;
    for (int j = 0; j < (N4CH + 255) / 256; ++j) {
        int loc = t + j * 256;
        if (loc < N4CH) {
            float4 a = f[o * N4CH + loc];
            ax += a.x * a.x; ay += a.y * a.y; az += a.z * a.z; aw += a.w * a.w;
        }
    }
    __shared__ float4 red[256];
    red[t] = make_float4(ax, ay, az, aw);
    __syncthreads();
    if (t < 16) {
        int t0 = (t - 8 * o) & 15;
        float sx = 0.f, sy = 0.f, sz = 0.f, sw = 0.f;
        #pragma unroll
        for (int j = 0; j < 16; ++j) {
            float4 a = red[t0 + 16 * j];
            sx += a.x; sy += a.y; sz += a.z; sw += a.w;
        }
        float* dst = partial + ((size_t)(b * OCT + o)) * D_ + 4 * t;
        dst[0] = sx; dst[1] = sy; dst[2] = sz; dst[3] = sw;
    }
}

__global__ __launch_bounds__(256) void norms_combine_kernel(const float* __restrict__ partial,
                                                            const float* __restrict__ codes,
                                                            float* __restrict__ inv_norm,
                                                            float* __restrict__ hns,
                                                            unsigned char* __restrict__ ksrt,
                                                            float* __restrict__ scodes) {
    int t = threadIdx.x;
    if (blockIdx.x == B_) {
        __shared__ float shn[KC];
        float myhn = 0.f;
        if (t < KC) {
            float s = 0.f;
            #pragma unroll 8
            for (int d = 0; d < D_; ++d) { float c = codes[t * D_ + d]; s += c * c; }
            myhn = 0.5f * s;
            shn[t] = myhn;
        }
        __syncthreads();
        if (t < KC) {
            int rank = 0;
            for (int j = 0; j < KC; ++j) {
                float h = shn[j];
                rank += (h < myhn) || (h == myhn && j < t);
            }
            hns[rank] = myhn;
            ksrt[rank] = (unsigned char)t;
            const float4* src = (const float4*)(codes + t * D_);
            float4* dst = (float4*)(scodes + rank * D_);
            #pragma unroll
            for (int j = 0; j < 16; ++j) dst[j] = src[j];
        }
        return;
    }
    int b = blockIdx.x;
    if (t < D_) {
        float s = 0.f;
        #pragma unroll
        for (int o = 0; o < OCT; ++o) s += partial[((size_t)(b * OCT + o)) * D_ + t];
        inv_norm[b * D_ + t] = 1.f / fmaxf(sqrtf(s), 1e-12f);
    }
}

__global__ __launch_bounds__(256) void assign_kernel(const float* __restrict__ feat,
                                                     const float* __restrict__ scodes,
                                                     const float* __restrict__ inv_norm,
                                                     const float* __restrict__ hns,
                                                     const unsigned char* __restrict__ ksrt,
                                                     unsigned char* __restrict__ kout,
                                                     float* __restrict__ rinvout,
                                                     unsigned short* __restrict__ rankout,
                                                     int* __restrict__ counts) {
    __shared__ float4 lc[SLIM * 16];
    __shared__ float  lhns[KC];
    __shared__ unsigned char lks[KC];
    __shared__ int hist[2 * KC];
    __shared__ int gbase[2 * KC];
    int t = threadIdx.x;
    const float4* sc4 = (const float4*)scodes;
    for (int i = t; i < SLIM * 16; i += 256) lc[i] = sc4[i];
    for (int i = t; i < KC; i += 256) { lhns[i] = hns[i]; lks[i] = ksrt[i]; }
    for (int i = t; i < 2 * KC; i += 256) hist[i] = 0;
    __syncthreads();

    int p = blockIdx.x * 256 + t;
    int b = p / NPB;
    int bfirst = (blockIdx.x * 256) / NPB;
    int lb = b - bfirst;

    float v[D_];
    float q = 0.f;
    {
        const float4* f0 = (const float4*)(feat + (size_t)p * D_);
        const float4* n0 = (const float4*)(inv_norm + b * D_);
        #pragma unroll
        for (int j = 0; j < 16; ++j) {
            float4 a = f0[j], w = n0[j];
            v[4*j+0] = a.x * w.x; v[4*j+1] = a.y * w.y;
            v[4*j+2] = a.z * w.z; v[4*j+3] = a.w * w.w;
            q += v[4*j+0]*v[4*j+0] + v[4*j+1]*v[4*j+1]
               + v[4*j+2]*v[4*j+2] + v[4*j+3]*v[4*j+3];
        }
    }
    float bw = sqrtf(q);
    float best = -3.0e38f;
    int kb = 0;
    int i = 0;
    for (; i < SLIM; ++i) {
        float hn = lhns[i];
        float bnd = fmaf(bw, sqrtf(hn + hn), -hn);
        if (__all(bnd + 1e-3f < best)) break;
        float a0 = 0.f, a1 = 0.f, a2 = 0.f, a3 = 0.f;
        #pragma unroll
        for (int j = 0; j < 16; ++j) {
            float4 c = lc[i * 16 + j];
            a0 = fmaf(v[4*j+0], c.x, a0); a1 = fmaf(v[4*j+1], c.y, a1);
            a2 = fmaf(v[4*j+2], c.z, a2); a3 = fmaf(v[4*j+3], c.w, a3);
        }
        float s = (a0 + a1) + (a2 + a3) - hn;
        if (s > best) { best = s; kb = i; }
    }
    if (i == SLIM) {
        for (; i < KC; ++i) {
            float hn = lhns[i];
            float bnd = fmaf(bw, sqrtf(hn + hn), -hn);
            if (__all(bnd + 1e-3f < best)) break;
            float a0 = 0.f, a1 = 0.f, a2 = 0.f, a3 = 0.f;
            #pragma unroll
            for (int j = 0; j < 16; ++j) {
                float4 c = sc4[i * 16 + j];
                a0 = fmaf(v[4*j+0], c.x, a0); a1 = fmaf(v[4*j+1], c.y, a1);
                a2 = fmaf(v[4*j+2], c.z, a2); a3 = fmaf(v[4*j+3], c.w, a3);
            }
            float s = (a0 + a1) + (a2 + a3) - hn;
            if (s > best) { best = s; kb = i; }
        }
    }
    int k0 = (int)lks[kb];
    float rinv = 1.f / (sqrtf(fmaxf(q - 2.f * best, 0.f)) + 1e-8f);
    kout[p] = (unsigned char)k0;
    rinvout[p] = rinv;
    int rloc = atomicAdd(&hist[lb * KC + k0], 1);
    __syncthreads();
    for (int j2 = t; j2 < 2 * KC; j2 += 256) {
        int h = hist[j2];
        if (h > 0) gbase[j2] = atomicAdd(&counts[bfirst * KC + j2], h);
    }
    __syncthreads();
    rankout[p] = (unsigned short)(gbase[lb * KC + k0] + rloc);
}

__global__ __launch_bounds__(256) void prefix_kernel(const int* __restrict__ counts,
                                                     int* __restrict__ base) {
    __shared__ int lcnt[KC];
    __shared__ int lbase[KC];
    int b = blockIdx.x, t = threadIdx.x;
    if (t < KC) lcnt[t] = counts[b * KC + t];
    __syncthreads();
    if (t == 0) {
        int run = 0;
        for (int k = 0; k < KC; ++k) { lbase[k] = run; run += lcnt[k]; }
    }
    __syncthreads();
    if (t < KC) base[b * KC + t] = lbase[t];
}

__global__ __launch_bounds__(256) void scatter_kernel(const unsigned char* __restrict__ kout,
                                                      const float* __restrict__ rinvout,
                                                      const unsigned short* __restrict__ rankout,
                                                      const int* __restrict__ base,
                                                      unsigned short* __restrict__ spidx,
                                                      float* __restrict__ srinv,
                                                      unsigned char* __restrict__ skbuf) {
    int p = blockIdx.x * 256 + threadIdx.x;
    if (p >= NPTS) return;
    int b = p / NPB;
    int k = (int)kout[p];
    int pos = b * NPB + base[b * KC + k] + (int)rankout[p];
    spidx[pos] = (unsigned short)(p - b * NPB);
    srinv[pos] = rinvout[p];
    skbuf[pos] = (unsigned char)k;
}

__global__ __launch_bounds__(256) void aggregate_kernel(const float* __restrict__ feat,
                                                        const unsigned short* __restrict__ spidx,
                                                        const unsigned char* __restrict__ skbuf,
                                                        const float* __restrict__ srinv,
                                                        float* __restrict__ vacc,
                                                        float* __restrict__ Sacc) {
    int wv = threadIdx.x >> 6, lane = threadIdx.x & 63;
    int chunk = blockIdx.x * 4 + wv;
    if (chunk >= B_ * CHPB) return;
    int b = chunk / CHPB, j = chunk % CHPB;
    int c0 = j * 64;
    int len = NPB - c0; if (len > 64) len = 64;
    int sbase = b * NPB;
    int pos = sbase + c0 + ((lane < len) ? lane : 0);
    int myp = (int)spidx[pos];
    int myk = (int)skbuf[pos];
    float myr = srinv[pos];
    const float* fb = feat + (size_t)sbase * D_ + lane;

    float acc = 0.f, Sr = 0.f;
    int kcur = -1;
    for (int i = 0; i < len; i += 4) {
        int n = len - i; if (n > 4) n = 4;
        float x[4], rr[4];
        int kk[4];
        #pragma unroll
        for (int u = 0; u < 4; ++u) {
            if (u < n) {
                int pp = __shfl(myp, i + u);
                kk[u] = __shfl(myk, i + u);
                rr[u] = __shfl(myr, i + u);
                x[u] = fb[(size_t)pp * D_];
            }
        }
        for (int u = 0; u < n; ++u) {
            if (kk[u] != kcur) {
                if (kcur >= 0) {
                    atomicAdd(vacc + ((size_t)b * KC + kcur) * D_ + lane, acc);
                    if (lane == 0) atomicAdd(Sacc + b * KC + kcur, Sr);
                }
                kcur = kk[u]; acc = 0.f; Sr = 0.f;
            }
            acc = fmaf(x[u], rr[u], acc);
            Sr += rr[u];
        }
    }
    if (kcur >= 0) {
        atomicAdd(vacc + ((size_t)b * KC + kcur) * D_ + lane, acc);
        if (lane == 0) atomicAdd(Sacc + b * KC + kcur, Sr);
    }
}

__global__ __launch_bounds__(1024) void final_std_kernel(const float* __restrict__ vacc,
                                                         const float* __restrict__ Sacc,
                                                         const float* __restrict__ codes,
                                                         const float* __restrict__ inv_norm,
                                                         float* __restrict__ out) {
    __shared__ float val[KC * APAD];
    __shared__ float Sl[KC];
    __shared__ float invl[D_];
    __shared__ double rs[1024], rss[1024];
    int b = blockIdx.x, t = threadIdx.x;
    if (t < KC) Sl[t] = Sacc[b * KC + t];
    if (t < D_) invl[t] = inv_norm[b * D_ + t];
    __syncthreads();
    const float* va = vacc + (size_t)b * NV;
    double s = 0.0, ss = 0.0;
    for (int i = t; i < NV; i += 1024) {
        int k = i >> 6, d = i & 63;
        float v = invl[d] * va[i] - codes[i] * Sl[k];
        val[k * APAD + d] = v;
        s += (double)v;
        ss += (double)v * (double)v;
    }
    rs[t] = s; rss[t] = ss;
    __syncthreads();
    for (int off = 512; off > 0; off >>= 1) {
        if (t < off) { rs[t] += rs[t + off]; rss[t] += rss[t + off]; }
        __syncthreads();
    }
    __shared__ float fmean, fscale;
    if (t == 0) {
        double S = rs[0], SS = rss[0];
        double mean = S / (double)NV;
        double var = (SS - S * S / (double)NV) / (double)(NV - 1);
        double sd = sqrt(var > 0.0 ? var : 0.0);
        fmean = (float)mean;
        fscale = (float)(1.0 / (sd + 1e-8));
    }
    __syncthreads();
    float m = fmean, sc = fscale;
    float* row = out + (size_t)b * NV;
    for (int i = t; i < NV; i += 1024) {
        int k = i >> 6, d = i & 63;
        row[i] = (val[k * APAD + d] - m) * sc;
    }
}

extern "C" void kernel_launch(void* const* d_in, const int* in_sizes, int n_in,
                              void* d_out, int out_size, void* d_ws, size_t ws_size,
                              hipStream_t stream) {
    const float* feat  = (const float*)d_in[0];
    const float* codes = (const float*)d_in[1];
    float* out = (float*)d_out;

    char* ws = (char*)d_ws;
    float* partial        = (float*)(ws + OFF_PARTIAL);
    int*   counts         = (int*)  (ws + OFF_COUNTS);
    float* Sacc           = (float*)(ws + OFF_SACC);
    float* vacc           = (float*)(ws + OFF_VACC);
    float4* zbase         = (float4*)(ws + OFF_COUNTS);
    unsigned char* kout   = (unsigned char*)(ws + OFF_KOUT);
    float* rinvout        = (float*)(ws + OFF_RINV);
    unsigned short* rankp = (unsigned short*)(ws + OFF_RANK);
    unsigned short* spidx = (unsigned short*)(ws + OFF_SPIDX);
    float* srinv          = (float*)(ws + OFF_SRINV);
    unsigned char* skbuf  = (unsigned char*)(ws + OFF_SKBUF);
    unsigned int* bar     = (unsigned int*)(ws + OFF_BAR);
    float* hns            = (float*)(ws + OFF_HNS);
    unsigned char* ksrt   = (unsigned char*)(ws + OFF_KSRT);
    float* inv_norm       = (float*)(ws + OFF_INVN);
    float* scodes         = (float*)(ws + OFF_SCODES);
    int*   basep          = (int*)  (ws + OFF_BASEP);

    int dev = 0, numCU = 0, occ = 0, grid = 0;
    if (hipGetDevice(&dev) == hipSuccess &&
        hipDeviceGetAttribute(&numCU, hipDeviceAttributeMultiprocessorCount, dev) == hipSuccess &&
        hipOccupancyMaxActiveBlocksPerMultiprocessor(&occ, (const void*)vlad_mega, 256, 0) == hipSuccess &&
        numCU > 0 && occ > 0) {
        grid = occ * numCU;
        if (grid > 1024) grid = 1024;
    }

    if (grid >= 64) {
        hipLaunchKernelGGL(init_bar_kernel, dim3(1), dim3(64), 0, stream, bar);
        hipLaunchKernelGGL(vlad_mega, dim3(grid), dim3(256), 0, stream,
                           feat, codes, partial, counts, Sacc, vacc, zbase,
                           kout, rinvout, rankp, spidx, srinv, skbuf,
                           hns, ksrt, scodes, bar, out);
    } else {
        // proven round-7 chain
        hipLaunchKernelGGL(norms_part_kernel, dim3(B_ * OCT + ZBLK), dim3(256), 0, stream,
                           feat, partial, zbase);
        hipLaunchKernelGGL(norms_combine_kernel, dim3(B_ + 1), dim3(256), 0, stream,
                           partial, codes, inv_norm, hns, ksrt, scodes);
        hipLaunchKernelGGL(assign_kernel, dim3(NBLK), dim3(256), 0, stream,
                           feat, scodes, inv_norm, hns, ksrt, kout, rinvout, rankp, counts);
        hipLaunchKernelGGL(prefix_kernel, dim3(B_), dim3(256), 0, stream, counts, basep);
        hipLaunchKernelGGL(scatter_kernel, dim3((NPTS + 255) / 256), dim3(256), 0, stream,
                           kout, rinvout, rankp, basep, spidx, srinv, skbuf);
        hipLaunchKernelGGL(aggregate_kernel, dim3((B_ * CHPB + 3) / 4), dim3(256), 0, stream,
                           feat, spidx, skbuf, srinv, vacc, Sacc);
        hipLaunchKernelGGL(final_std_kernel, dim3(B_), dim3(1024), 0, stream,
                           vacc, Sacc, codes, inv_norm, out);
    }
}

// Round 10
// 106.394 us; speedup vs baseline: 5.1001x; 5.1001x over previous
//
#include <hip/hip_runtime.h>
#include <math.h>

#define B_   64
#define NPB  3468            // points (visual words) per batch
#define NPTS (B_ * NPB)      // 221952
#define KC   248
#define D_   64
#define NV   (KC * D_)       // 15872 per-batch vlad elements
#define OCT  8               // norms: chunks per batch
#define N4PB (NPB * D_ / 4)  // 55488 float4s per batch
#define N4CH (N4PB / OCT)    // 6936 float4s per chunk
#define CHPB 55              // aggregation chunks per batch
#define APAD 65
#define SLIM 64              // sorted code rows staged in LDS
#define NBLK (NPTS / 256)    // 867 point-blocks
#define ZBLK 128             // zeroing blocks in prep
#define ZN4  261888          // float4s in zero region (counts+Sacc+vacc)

// ------------------------- workspace offsets (bytes) -------------------------
#define OFF_PARTIAL 0u        // 131072
#define OFF_COUNTS  131072u   // 63488   -- zero region start
#define OFF_SACC    194560u   // 63488
#define OFF_VACC    258048u   // 4063232 -- zero region end = 4321280
#define OFF_KOUT    4321280u  // 221952
#define OFF_RINV    4543232u  // 887808
#define OFF_RANK    5431040u  // 443904
#define OFF_SPU     5874944u  // 887808  (packed sorted: pidx<<8 | k)
#define OFF_HNS     6762752u  // 1024
#define OFF_KSRT    6763776u  // 256
#define OFF_SCODES  6764032u  // 16384 (first SLIM sorted rows only) -> 6780416

// ===== pass 1: sumsq partials (512 blk) + code sort (1 blk) + zeroing (128 blk)
__global__ __launch_bounds__(256) void prep_kernel(const float* __restrict__ feat,
                                                   const float* __restrict__ codes,
                                                   float* __restrict__ partial,
                                                   float* __restrict__ hns,
                                                   unsigned char* __restrict__ ksrt,
                                                   float* __restrict__ scodes,
                                                   float4* __restrict__ zbase) {
    int t = threadIdx.x;
    if (blockIdx.x > B_ * OCT) {            // zeroing blocks
        int z = blockIdx.x - (B_ * OCT + 1);
        const float4 zf = make_float4(0.f, 0.f, 0.f, 0.f);
        for (int i = z * 256 + t; i < ZN4; i += ZBLK * 256) zbase[i] = zf;
        return;
    }
    if (blockIdx.x == B_ * OCT) {           // code half-norms + hn-sort block
        __shared__ float shn[KC];
        int lane = t & 63, wvid = t >> 6;
        for (int base2 = 0; base2 < KC * D_; base2 += 256) {
            float c = codes[base2 + t];
            float cc = c * c;
            #pragma unroll
            for (int off = 32; off > 0; off >>= 1) cc += __shfl_down(cc, off);
            if (lane == 0) shn[(base2 >> 6) + wvid] = 0.5f * cc;
        }
        __syncthreads();
        if (t < KC) {
            float myhn = shn[t];
            int rank = 0;
            for (int j = 0; j < KC; ++j) {
                float h = shn[j];
                rank += (h < myhn) || (h == myhn && j < t);
            }
            hns[rank] = myhn;
            ksrt[rank] = (unsigned char)t;
            if (rank < SLIM) {              // stage only rows assign keeps in LDS
                const float4* src = (const float4*)(codes + t * D_);
                float4* dst = (float4*)(scodes + rank * D_);
                #pragma unroll
                for (int j = 0; j < 16; ++j) dst[j] = src[j];
            }
        }
        return;
    }
    // sum-of-squares partial for (b, chunk o)
    int b = blockIdx.x >> 3, o = blockIdx.x & 7;
    const float4* f = (const float4*)(feat + (size_t)b * (NPB * D_));
    float ax = 0.f, ay = 0.f, az = 0.f, aw = 0.f;
    for (int j = 0; j < (N4CH + 255) / 256; ++j) {
        int loc = t + j * 256;
        if (loc < N4CH) {
            float4 a = f[o * N4CH + loc];
            ax += a.x * a.x; ay += a.y * a.y; az += a.z * a.z; aw += a.w * a.w;
        }
    }
    __shared__ float4 red[256];
    red[t] = make_float4(ax, ay, az, aw);
    __syncthreads();
    if (t < 16) {   // dim-group of i4 = (t + 8o) & 15
        int t0 = (t - 8 * o) & 15;
        float sx = 0.f, sy = 0.f, sz = 0.f, sw = 0.f;
        #pragma unroll
        for (int j = 0; j < 16; ++j) {
            float4 a = red[t0 + 16 * j];
            sx += a.x; sy += a.y; sz += a.z; sw += a.w;
        }
        float* dst = partial + ((size_t)(b * OCT + o)) * D_ + 4 * t;
        dst[0] = sx; dst[1] = sy; dst[2] = sz; dst[3] = sw;
    }
}

// ===== pass 2: assignment (per-block inv-norm derive + CS pruning + 2-level rank)
__global__ __launch_bounds__(256) void assign_kernel(const float* __restrict__ feat,
                                                     const float* __restrict__ codes,
                                                     const float* __restrict__ scodes,
                                                     const float* __restrict__ partial,
                                                     const float* __restrict__ hns,
                                                     const unsigned char* __restrict__ ksrt,
                                                     unsigned char* __restrict__ kout,
                                                     float* __restrict__ rinvout,
                                                     unsigned short* __restrict__ rankout,
                                                     int* __restrict__ counts) {
    __shared__ float4 lc[SLIM * 16];     // 16384 B: first SLIM sorted rows
    __shared__ float  lhns[KC];
    __shared__ float  invl[128];         // <=2 batches x 64 dims
    __shared__ unsigned char lks[KC];
    __shared__ int hist[2 * KC];
    __shared__ int gbase[2 * KC];
    int t = threadIdx.x;
    const float4* sc4 = (const float4*)scodes;
    const float4* c4  = (const float4*)codes;
    int bfirst = (blockIdx.x * 256) / NPB;
    for (int i = t; i < SLIM * 16; i += 256) lc[i] = sc4[i];
    for (int i = t; i < KC; i += 256) { lhns[i] = hns[i]; lks[i] = ksrt[i]; }
    if (t < 128) {
        int lb2 = t >> 6, d = t & 63;
        int b2 = bfirst + lb2;
        if (b2 < B_) {
            float s = 0.f;
            #pragma unroll
            for (int o = 0; o < OCT; ++o)
                s += partial[((size_t)(b2 * OCT + o)) * D_ + d];
            invl[t] = 1.f / fmaxf(sqrtf(s), 1e-12f);
        }
    }
    for (int i = t; i < 2 * KC; i += 256) hist[i] = 0;
    __syncthreads();

    int p = blockIdx.x * 256 + t;        // grid exact: 867*256 == NPTS
    int b = p / NPB;
    int lb = b - bfirst;

    float v[D_];
    float q = 0.f;
    {
        const float4* f0 = (const float4*)(feat + (size_t)p * D_);
        const float4* n0 = ((const float4*)invl) + lb * 16;
        #pragma unroll
        for (int j = 0; j < 16; ++j) {
            float4 a = f0[j], w = n0[j];
            v[4*j+0] = a.x * w.x; v[4*j+1] = a.y * w.y;
            v[4*j+2] = a.z * w.z; v[4*j+3] = a.w * w.w;
            q += v[4*j+0]*v[4*j+0] + v[4*j+1]*v[4*j+1]
               + v[4*j+2]*v[4*j+2] + v[4*j+3]*v[4*j+3];
        }
    }
    float bw = sqrtf(q);
    float best = -3.0e38f;
    int kb = 0;
    int i = 0;
    for (; i < SLIM; ++i) {
        float hn = lhns[i];
        float bnd = fmaf(bw, sqrtf(hn + hn), -hn);   // Cauchy-Schwarz bound
        if (__all(bnd + 1e-3f < best)) break;        // monotone in i -> safe
        float a0 = 0.f, a1 = 0.f, a2 = 0.f, a3 = 0.f;
        #pragma unroll
        for (int j = 0; j < 16; ++j) {
            float4 c = lc[i * 16 + j];
            a0 = fmaf(v[4*j+0], c.x, a0); a1 = fmaf(v[4*j+1], c.y, a1);
            a2 = fmaf(v[4*j+2], c.z, a2); a3 = fmaf(v[4*j+3], c.w, a3);
        }
        float s = (a0 + a1) + (a2 + a3) - hn;
        if (s > best) { best = s; kb = i; }
    }
    if (i == SLIM) {                     // rare tail: broadcast reads of codes
        for (; i < KC; ++i) {
            float hn = lhns[i];
            float bnd = fmaf(bw, sqrtf(hn + hn), -hn);
            if (__all(bnd + 1e-3f < best)) break;
            const float4* cr = c4 + (int)lks[i] * 16;
            float a0 = 0.f, a1 = 0.f, a2 = 0.f, a3 = 0.f;
            #pragma unroll
            for (int j = 0; j < 16; ++j) {
                float4 c = cr[j];
                a0 = fmaf(v[4*j+0], c.x, a0); a1 = fmaf(v[4*j+1], c.y, a1);
                a2 = fmaf(v[4*j+2], c.z, a2); a3 = fmaf(v[4*j+3], c.w, a3);
            }
            float s = (a0 + a1) + (a2 + a3) - hn;
            if (s > best) { best = s; kb = i; }
        }
    }
    int k0 = (int)lks[kb];
    float rinv = 1.f / (sqrtf(fmaxf(q - 2.f * best, 0.f)) + 1e-8f);
    kout[p] = (unsigned char)k0;
    rinvout[p] = rinv;
    int rloc = atomicAdd(&hist[lb * KC + k0], 1);    // block-local rank
    __syncthreads();
    for (int j2 = t; j2 < 2 * KC; j2 += 256) {       // reserve global ranges
        int h = hist[j2];
        if (h > 0) gbase[j2] = atomicAdd(&counts[bfirst * KC + j2], h);
    }
    __syncthreads();
    rankout[p] = (unsigned short)(gbase[lb * KC + k0] + rloc);
}

// ===== pass 3: scatter into sorted order (per-block prefix recompute)
__global__ __launch_bounds__(256) void scatter_kernel(const unsigned char* __restrict__ kout,
                                                      const unsigned short* __restrict__ rankout,
                                                      const int* __restrict__ counts,
                                                      unsigned int* __restrict__ spu) {
    __shared__ int lcnt[2 * KC];
    __shared__ int lbase[2 * KC];
    int t = threadIdx.x;
    int bfirst = (blockIdx.x * 256) / NPB, blast = (blockIdx.x * 256 + 255) / NPB;
    int nb = blast - bfirst + 1;                     // 1 or 2
    for (int i = t; i < nb * KC; i += 256) lcnt[i] = counts[bfirst * KC + i];
    __syncthreads();
    if (t < nb) {                                    // serial 248-scan per batch
        int run = 0;
        for (int k = 0; k < KC; ++k) { lbase[t * KC + k] = run; run += lcnt[t * KC + k]; }
    }
    __syncthreads();
    int p = blockIdx.x * 256 + t;
    int b = p / NPB;
    int lb = b - bfirst;
    int k = (int)kout[p];
    int pos = b * NPB + lbase[lb * KC + k] + (int)rankout[p];
    spu[pos] = ((unsigned int)(p - b * NPB) << 8) | (unsigned int)k;
}

// ===== pass 4: load-balanced segmented aggregation (skew-proof)
__global__ __launch_bounds__(256) void aggregate_kernel(const float* __restrict__ feat,
                                                        const unsigned int* __restrict__ spu,
                                                        const float* __restrict__ rinvout,
                                                        float* __restrict__ vacc,
                                                        float* __restrict__ Sacc) {
    int wv = threadIdx.x >> 6, lane = threadIdx.x & 63;
    int chunk = blockIdx.x * 4 + wv;
    if (chunk >= B_ * CHPB) return;
    int b = chunk / CHPB, j = chunk % CHPB;
    int c0 = j * 64;
    int len = NPB - c0; if (len > 64) len = 64;
    int sbase = b * NPB;
    int pos = sbase + c0 + ((lane < len) ? lane : 0);
    unsigned int myu = spu[pos];
    float myr = rinvout[sbase + (int)(myu >> 8)];
    const float* fb = feat + (size_t)sbase * D_ + lane;

    float acc = 0.f, Sr = 0.f;
    int kcur = -1;
    for (int i = 0; i < len; i += 4) {
        int n = len - i; if (n > 4) n = 4;
        float x[4], rr[4];
        int kk[4];
        #pragma unroll
        for (int u = 0; u < 4; ++u) {
            if (u < n) {
                unsigned int uu = __shfl(myu, i + u);
                rr[u] = __shfl(myr, i + u);
                kk[u] = (int)(uu & 255u);
                x[u] = fb[(size_t)(uu >> 8) * D_];
            }
        }
        for (int u = 0; u < n; ++u) {
            if (kk[u] != kcur) {
                if (kcur >= 0) {
                    atomicAdd(vacc + ((size_t)b * KC + kcur) * D_ + lane, acc);
                    if (lane == 0) atomicAdd(Sacc + b * KC + kcur, Sr);
                }
                kcur = kk[u]; acc = 0.f; Sr = 0.f;
            }
            acc = fmaf(x[u], rr[u], acc);
            Sr += rr[u];
        }
    }
    if (kcur >= 0) {
        atomicAdd(vacc + ((size_t)b * KC + kcur) * D_ + lane, acc);
        if (lane == 0) atomicAdd(Sacc + b * KC + kcur, Sr);
    }
}

// ===== pass 5: finalize vlad + per-batch standardize (fused; derives inv-norm)
__global__ __launch_bounds__(1024) void final_std_kernel(const float* __restrict__ vacc,
                                                         const float* __restrict__ Sacc,
                                                         const float* __restrict__ codes,
                                                         const float* __restrict__ partial,
                                                         float* __restrict__ out) {
    __shared__ float val[KC * APAD];   // 64480 B
    __shared__ float Sl[KC];
    __shared__ float invl[D_];
    __shared__ double rs[1024], rss[1024];
    int b = blockIdx.x, t = threadIdx.x;
    if (t < KC) Sl[t] = Sacc[b * KC + t];
    if (t < D_) {
        float s = 0.f;
        #pragma unroll
        for (int o = 0; o < OCT; ++o)
            s += partial[((size_t)(b * OCT + o)) * D_ + t];
        invl[t] = 1.f / fmaxf(sqrtf(s), 1e-12f);
    }
    __syncthreads();
    const float* va = vacc + (size_t)b * NV;
    double s = 0.0, ss = 0.0;
    for (int i = t; i < NV; i += 1024) {
        int k = i >> 6, d = i & 63;
        float v = invl[d] * va[i] - codes[i] * Sl[k];
        val[k * APAD + d] = v;
        s += (double)v;
        ss += (double)v * (double)v;
    }
    rs[t] = s; rss[t] = ss;
    __syncthreads();
    for (int off = 512; off > 0; off >>= 1) {
        if (t < off) { rs[t] += rs[t + off]; rss[t] += rss[t + off]; }
        __syncthreads();
    }
    __shared__ float fmean, fscale;
    if (t == 0) {
        double S = rs[0], SS = rss[0];
        double mean = S / (double)NV;
        double var = (SS - S * S / (double)NV) / (double)(NV - 1);
        double sd = sqrt(var > 0.0 ? var : 0.0);
        fmean = (float)mean;
        fscale = (float)(1.0 / (sd + 1e-8));
    }
    __syncthreads();
    float m = fmean, sc = fscale;
    float* row = out + (size_t)b * NV;
    for (int i = t; i < NV; i += 1024) {
        int k = i >> 6, d = i & 63;
        row[i] = (val[k * APAD + d] - m) * sc;
    }
}

extern "C" void kernel_launch(void* const* d_in, const int* in_sizes, int n_in,
                              void* d_out, int out_size, void* d_ws, size_t ws_size,
                              hipStream_t stream) {
    const float* feat  = (const float*)d_in[0];
    const float* codes = (const float*)d_in[1];
    float* out = (float*)d_out;

    char* ws = (char*)d_ws;
    float* partial        = (float*)(ws + OFF_PARTIAL);
    int*   counts         = (int*)  (ws + OFF_COUNTS);
    float* Sacc           = (float*)(ws + OFF_SACC);
    float* vacc           = (float*)(ws + OFF_VACC);
    float4* zbase         = (float4*)(ws + OFF_COUNTS);
    unsigned char* kout   = (unsigned char*)(ws + OFF_KOUT);
    float* rinvout        = (float*)(ws + OFF_RINV);
    unsigned short* rankp = (unsigned short*)(ws + OFF_RANK);
    unsigned int* spu     = (unsigned int*)(ws + OFF_SPU);
    float* hns            = (float*)(ws + OFF_HNS);
    unsigned char* ksrt   = (unsigned char*)(ws + OFF_KSRT);
    float* scodes         = (float*)(ws + OFF_SCODES);

    hipLaunchKernelGGL(prep_kernel, dim3(B_ * OCT + 1 + ZBLK), dim3(256), 0, stream,
                       feat, codes, partial, hns, ksrt, scodes, zbase);
    hipLaunchKernelGGL(assign_kernel, dim3(NBLK), dim3(256), 0, stream,
                       feat, codes, scodes, partial, hns, ksrt,
                       kout, rinvout, rankp, counts);
    hipLaunchKernelGGL(scatter_kernel, dim3(NBLK), dim3(256), 0, stream,
                       kout, rankp, counts, spu);
    hipLaunchKernelGGL(aggregate_kernel, dim3((B_ * CHPB + 3) / 4), dim3(256), 0, stream,
                       feat, spu, rinvout, vacc, Sacc);
    hipLaunchKernelGGL(final_std_kernel, dim3(B_), dim3(1024), 0, stream,
                       vacc, Sacc, codes, partial, out);
}